// Round 7
// baseline (79.732 us; speedup 1.0000x reference)
//
#include <hip/hip_runtime.h>
#include <stdint.h>

#define NE 64        // real experts (ids in [0,64))
#define E  65        // num_experts + 1 (expert 64 always empty)
#define BLK 128      // block_size
#define WPB 4        // waves per 256-thread block
#define THREADS 256
#define TPB 4096     // tokens per block
#define TPT 16       // tokens per thread (contiguous -> stability by thread order)
#define CHB 64       // blocks per scan chunk

// ---- k_hist: per-block histogram via per-wave LDS atomics -> bcnt[b][e] ----
__global__ void __launch_bounds__(THREADS, 8) k_hist(const int* __restrict__ topk,
                                                     int* __restrict__ bcnt) {
    __shared__ int hist[WPB][NE];
    const int tid = threadIdx.x, w = tid >> 6, lane = tid & 63;
    hist[w][lane] = 0;                       // wave-private row, no barrier needed
    const int base = blockIdx.x * TPB + w * 1024;
#pragma unroll
    for (int it = 0; it < 4; ++it) {
        int4 v = *(const int4*)(topk + base + it * 256 + lane * 4);
        atomicAdd(&hist[w][v.x], 1);
        atomicAdd(&hist[w][v.y], 1);
        atomicAdd(&hist[w][v.z], 1);
        atomicAdd(&hist[w][v.w], 1);
    }
    __syncthreads();
    if (tid < NE)
        bcnt[blockIdx.x * NE + tid] =
            hist[0][tid] + hist[1][tid] + hist[2][tid] + hist[3][tid];
}

// ---- k_scan1: in-chunk exclusive prefix of bcnt over CHB blocks; chunk totals ----
__global__ void k_scan1(int* __restrict__ bcnt, int* __restrict__ ctot) {
    __shared__ int tile[CHB * NE];           // 16 KB
    const int c = blockIdx.x, tid = threadIdx.x;
    for (int i = tid; i < CHB * NE; i += THREADS) tile[i] = bcnt[c * CHB * NE + i];
    __syncthreads();
    if (tid < NE) {
        int acc = 0;
#pragma unroll 8
        for (int j = 0; j < CHB; ++j) { int o = tile[j * NE + tid]; tile[j * NE + tid] = acc; acc += o; }
        ctot[c * NE + tid] = acc;
    }
    __syncthreads();
    for (int i = tid; i < CHB * NE; i += THREADS) bcnt[c * CHB * NE + i] = tile[i];
}

// ---- k_scan2: chunk-level scan + counts / off_pad / cum_pad / npp ----
__global__ void k_scan2(int* __restrict__ ctot, int* __restrict__ counts,
                        int* __restrict__ off_pad, int* __restrict__ cum_pad,
                        int* __restrict__ npp, int nc) {
    __shared__ int ct[32 * NE];              // nc <= 32
    const int tid = threadIdx.x;
    for (int i = tid; i < nc * NE; i += THREADS) ct[i] = ctot[i];
    __syncthreads();
    if (tid < NE) {
        int acc = 0;
        for (int c = 0; c < nc; ++c) { int o = ct[c * NE + tid]; ct[c * NE + tid] = acc; acc += o; }
        counts[tid] = acc;
    }
    if (tid == NE) counts[NE] = 0;           // expert 64 never occurs
    __syncthreads();
    for (int i = tid; i < nc * NE; i += THREADS) ctot[i] = ct[i];
    if (tid == 0) {
        int run = 0;
        for (int e = 0; e < E; ++e) {
            int p = (counts[e] + BLK - 1) & ~(BLK - 1);
            off_pad[e] = run;
            run += p;
            cum_pad[e] = run;
        }
        *npp = run;
    }
}

// ---- k_sort: thread-ownership stable counting sort, staged in LDS ----
// p16[e][lane] layout: bank = lane/2 for any e -> conflict-free counting AND scan.
__global__ void __launch_bounds__(THREADS) k_sort(
        const int* __restrict__ topk, const int* __restrict__ bpre,
        const int* __restrict__ ctot, const int* __restrict__ counts,
        const int* __restrict__ off_pad, const int* __restrict__ cum_pad,
        int* __restrict__ sorted, int* __restrict__ eids,
        int nb, int M, int T, int epb) {
    __shared__ unsigned short p16[WPB][NE][64];   // 32 KB wave-private counters
    __shared__ int sbuf[TPB];                     // 16 KB staged sorted tokens
    __shared__ int wt[WPB][NE];                   // 1 KB wave totals
    __shared__ int cps[E];
    const int tid = threadIdx.x, w = tid >> 6, lane = tid & 63;
    const int b = blockIdx.x, c = b / CHB;

    // this thread's 16 contiguous tokens (token order == thread order)
    const int4* tp = (const int4*)(topk + b * TPB);
    int4 ta = tp[tid * 4], tb = tp[tid * 4 + 1], tc = tp[tid * 4 + 2], td = tp[tid * 4 + 3];

    if (tid < E) cps[tid] = cum_pad[tid];

    // zero this wave's counter matrix -- SAME-TYPE stores (no aliasing UB)
    {
        unsigned short* f = &p16[w][0][0];        // 4096 u16 per wave
#pragma unroll
        for (int k = 0; k < 64; ++k) f[k * 64 + lane] = 0;
    }
    __syncthreads();   // compiler-level fence: zeroing complete before counting

    // count: 1 LDS RMW per token, each lane owns column `lane`
#define CNT1(EV) { unsigned short* cl = &p16[w][(EV) & 63][lane]; *cl = (unsigned short)(*cl + 1); }
    CNT1(ta.x) CNT1(ta.y) CNT1(ta.z) CNT1(ta.w)
    CNT1(tb.x) CNT1(tb.y) CNT1(tb.z) CNT1(tb.w)
    CNT1(tc.x) CNT1(tc.y) CNT1(tc.z) CNT1(tc.w)
    CNT1(td.x) CNT1(td.y) CNT1(td.z) CNT1(td.w)
#undef CNT1

    // per-expert exclusive scan over lanes (in place); capture own-expert wave total
    int mytot = 0;
#pragma unroll 4
    for (int e = 0; e < NE; ++e) {
        int cnt = p16[w][e][lane];
        int incl = cnt;
#pragma unroll
        for (int d = 1; d < 64; d <<= 1) { int t = __shfl_up(incl, d); if (lane >= d) incl += t; }
        p16[w][e][lane] = (unsigned short)(incl - cnt);
        int tot = __shfl(incl, 63);
        if (lane == e) mytot = tot;
    }
    wt[w][lane] = mytot;
    __syncthreads();

    // cross-wave offsets + block totals (lane owns expert `lane`)
    int woff = 0, btot = 0;
#pragma unroll
    for (int w2 = 0; w2 < WPB; ++w2) { int v = wt[w2][lane]; woff += (w2 < w) ? v : 0; btot += v; }
    int incl = btot;
#pragma unroll
    for (int d = 1; d < 64; d <<= 1) { int t = __shfl_up(incl, d); if (lane >= d) incl += t; }
    int loc = incl - btot;                            // block-local segment start
    int dbase = off_pad[lane] + ctot[c * NE + lane] + bpre[b * NE + lane] - loc;
    int S = loc + woff;                               // wave's block-local start

    // walk own tokens in order: LDS RMW resumes from lane-exclusive base -> stable
#define PLACE(EV, IDX) { int e_ = (EV) & 63; unsigned short* cl = &p16[w][e_][lane]; \
        int r_ = *cl; *cl = (unsigned short)(r_ + 1); \
        int pos = (__shfl(S, e_) + r_) & (TPB - 1); \
        sbuf[pos] = (e_ << 12) | (tid * TPT + (IDX)); }
    PLACE(ta.x, 0)  PLACE(ta.y, 1)  PLACE(ta.z, 2)  PLACE(ta.w, 3)
    PLACE(tb.x, 4)  PLACE(tb.y, 5)  PLACE(tb.z, 6)  PLACE(tb.w, 7)
    PLACE(tc.x, 8)  PLACE(tc.y, 9)  PLACE(tc.z, 10) PLACE(tc.w, 11)
    PLACE(td.x, 12) PLACE(td.y, 13) PLACE(td.z, 14) PLACE(td.w, 15)
#undef PLACE
    __syncthreads();

    // write out: sequential LDS read, segmented-contiguous global write
    const int bstart = b * TPB;
#pragma unroll
    for (int k = 0; k < 16; ++k) {
        int j = k * THREADS + tid;
        int p = sbuf[j];
        int e = (p >> 12) & 63;              // defensive clamp: no wild stores
        int d = __shfl(dbase, e);            // dbase identical across waves
        sorted[d + j] = bstart + (p & 0xfff);
    }

    // epilogue A: this block's slice of expert_ids
    int total = cps[NE];
    if (tid < epb) {
        int j = b * epb + tid;
        if (j < nb) {
            int bs = j * BLK, r = 0;
            if (bs < total) {
                int lo = 0, hi = E;
                while (lo < hi) { int mid = (lo + hi) >> 1; if (cps[mid] <= bs) lo = mid + 1; else hi = mid; }
                r = lo;
            }
            eids[j] = r;
        }
    }
    // epilogue B: pad-gap fill (blocks 0..64) and tail fill (blocks 65..97)
    if (b < E) {
        int cc = counts[b];
        int pe = (cc + BLK - 1) & ~(BLK - 1);
        int len = pe - cc;                            // <= 127
        if (tid < len) sorted[off_pad[b] + cc + tid] = T;
    } else if (b < E + 33) {
        int i = total + (b - E) * THREADS + tid;
        if (i < M) sorted[i] = T;                     // tail <= 8255 < 33*256
    }
}

extern "C" void kernel_launch(void* const* d_in, const int* in_sizes, int n_in,
                              void* d_out, int out_size, void* d_ws, size_t ws_size,
                              hipStream_t stream) {
    const int* topk = (const int*)d_in[0];
    const int T = in_sizes[0];                       // 8388608 = 2048 * 4096
    const int M = T + E * (BLK - 1);
    const int nb = M / BLK;

    int* out = (int*)d_out;
    int* sorted = out;
    int* expert_ids = out + M;
    int* npp = out + M + nb;

    const int NB = T / TPB;                          // 2048 blocks
    const int NC = NB / CHB;                         // 32 chunks
    const int epb = (nb + NB - 1) / NB;              // expert_ids entries per block

    int* bcnt    = (int*)d_ws;                       // NB*NE (becomes in-chunk prefix)
    int* ctot    = bcnt + (size_t)NB * NE;           // NC*NE
    int* counts  = ctot + (size_t)NC * NE;           // E
    int* off_pad = counts + E;                       // E
    int* cum_pad = off_pad + E;                      // E

    k_hist<<<NB, THREADS, 0, stream>>>(topk, bcnt);
    k_scan1<<<NC, THREADS, 0, stream>>>(bcnt, ctot);
    k_scan2<<<1, THREADS, 0, stream>>>(ctot, counts, off_pad, cum_pad, npp, NC);
    k_sort<<<NB, THREADS, 0, stream>>>(topk, bcnt, ctot, counts, off_pad, cum_pad,
                                       sorted, expert_ids, nb, M, T, epb);
}

// Round 8
// 44.909 us; speedup vs baseline: 1.7754x; 1.7754x over previous
//
#include <hip/hip_runtime.h>
#include <stdint.h>

#define NE 64        // real experts (ids in [0,64))
#define E  65        // num_experts + 1 (expert 64 always empty)
#define BLK 128      // block_size
#define WPB 4        // waves per 256-thread block
#define THREADS 256
#define TPB 4096     // tokens per block
#define CHB 64       // blocks per scan chunk

// emulate match_any over 64 lanes for expert ids in [0,64): 6 ballots
__device__ __forceinline__ unsigned long long match_any6(int e) {
    unsigned long long m = ~0ull;
#pragma unroll
    for (int b = 0; b < 6; ++b) {
        unsigned long long bal = __ballot((e >> b) & 1);
        m &= ((e >> b) & 1) ? bal : ~bal;
    }
    return m;
}

// ---- k_hist: per-block histogram via per-wave LDS atomics -> bcnt[b][e] ----
__global__ void __launch_bounds__(THREADS, 8) k_hist(const int* __restrict__ topk,
                                                     int* __restrict__ bcnt) {
    __shared__ int hist[WPB][NE];
    const int tid = threadIdx.x, w = tid >> 6, lane = tid & 63;
    hist[w][lane] = 0;                       // wave-private row, no barrier needed
    const int base = blockIdx.x * TPB + w * 1024;
#pragma unroll
    for (int it = 0; it < 4; ++it) {
        int4 v = *(const int4*)(topk + base + it * 256 + lane * 4);
        atomicAdd(&hist[w][v.x & 63], 1);
        atomicAdd(&hist[w][v.y & 63], 1);
        atomicAdd(&hist[w][v.z & 63], 1);
        atomicAdd(&hist[w][v.w & 63], 1);
    }
    __syncthreads();
    if (tid < NE)
        bcnt[blockIdx.x * NE + tid] =
            hist[0][tid] + hist[1][tid] + hist[2][tid] + hist[3][tid];
}

// ---- k_scan1: in-chunk exclusive prefix of bcnt over CHB blocks; chunk totals ----
__global__ void k_scan1(int* __restrict__ bcnt, int* __restrict__ ctot) {
    __shared__ int tile[CHB * NE];           // 16 KB
    const int c = blockIdx.x, tid = threadIdx.x;
    for (int i = tid; i < CHB * NE; i += THREADS) tile[i] = bcnt[c * CHB * NE + i];
    __syncthreads();
    if (tid < NE) {
        int acc = 0;
#pragma unroll 8
        for (int j = 0; j < CHB; ++j) { int o = tile[j * NE + tid]; tile[j * NE + tid] = acc; acc += o; }
        ctot[c * NE + tid] = acc;
    }
    __syncthreads();
    for (int i = tid; i < CHB * NE; i += THREADS) bcnt[c * CHB * NE + i] = tile[i];
}

// ---- k_scan2: chunk-level scan + counts / off_pad / cum_pad / npp ----
__global__ void k_scan2(int* __restrict__ ctot, int* __restrict__ counts,
                        int* __restrict__ off_pad, int* __restrict__ cum_pad,
                        int* __restrict__ npp, int nc) {
    __shared__ int ct[32 * NE];              // nc <= 32
    const int tid = threadIdx.x;
    for (int i = tid; i < nc * NE; i += THREADS) ct[i] = ctot[i];
    __syncthreads();
    if (tid < NE) {
        int acc = 0;
        for (int c = 0; c < nc; ++c) { int o = ct[c * NE + tid]; ct[c * NE + tid] = acc; acc += o; }
        counts[tid] = acc;
    }
    if (tid == NE) counts[NE] = 0;           // expert 64 never occurs
    __syncthreads();
    for (int i = tid; i < nc * NE; i += THREADS) ctot[i] = ct[i];
    if (tid == 0) {
        int run = 0;
        for (int e = 0; e < E; ++e) {
            int p = (counts[e] + BLK - 1) & ~(BLK - 1);
            off_pad[e] = run;
            run += p;
            cum_pad[e] = run;
        }
        *npp = run;
    }
}

// ---- k_sort: fused rank (match_any leader-atomic) + block-staged scatter ----
// Per wave: stable ranks for its 1024 contiguous tokens, kept in 16 registers.
// Block combine -> 4096-token sbuf staging -> segmented-contiguous write-out.
__global__ void __launch_bounds__(THREADS) k_sort(
        const int* __restrict__ topk, const int* __restrict__ bpre,
        const int* __restrict__ ctot, const int* __restrict__ counts,
        const int* __restrict__ off_pad, const int* __restrict__ cum_pad,
        int* __restrict__ sorted, int* __restrict__ eids,
        int nb, int M, int T, int epb) {
    __shared__ int lrun[WPB][NE];    // per-wave running counters (rank core)
    __shared__ int wt[WPB][NE];      // wave totals
    __shared__ int sbuf[TPB];        // 16 KB staged sorted tokens
    __shared__ int cps[E];
    const int tid = threadIdx.x, w = tid >> 6, lane = tid & 63;
    const int b = blockIdx.x, c = b / CHB;

    if (tid < E) cps[tid] = cum_pad[tid];
    lrun[w][lane] = 0;               // wave-private row: same-wave DS order, no barrier

    const int wstart = b * TPB + w * 1024;
    const unsigned long long lt = (1ull << lane) - 1ull;

    // phase A: stable local ranks; leader atomicAdd returns running base
    // (same-wave DS atomics are program-ordered -> stability; no reg dep chain)
    int packed[16];
#pragma unroll
    for (int it = 0; it < 16; ++it) {
        int e = topk[wstart + it * 64 + lane] & 63;
        unsigned long long m = match_any6(e);
        int leader = (int)(__ffsll((long long)m) - 1);
        int r = __popcll(m & lt);
        int old_l = 0;
        if (lane == leader) old_l = atomicAdd(&lrun[w][e], __popcll(m));
        int bs = __shfl(old_l, leader);
        packed[it] = (e << 10) | (bs + r);           // wave-local rank < 1024
    }
    wt[w][lane] = lrun[w][lane];
    __syncthreads();

    // phase B: cross-wave offsets + block-local segment starts (lane owns expert lane)
    int woff = 0, btot = 0;
#pragma unroll
    for (int w2 = 0; w2 < WPB; ++w2) { int v = wt[w2][lane]; woff += (w2 < w) ? v : 0; btot += v; }
    int incl = btot;
#pragma unroll
    for (int d = 1; d < 64; d <<= 1) { int t = __shfl_up(incl, d); if (lane >= d) incl += t; }
    int loc = incl - btot;                            // block-local segment start
    int dbase = off_pad[lane] + ctot[c * NE + lane] + bpre[b * NE + lane] - loc;
    int S = loc + woff;                               // this wave's start in segment

    // phase C: place block-local token ids into LDS in sorted order
    const int wloc = w * 1024;
#pragma unroll
    for (int it = 0; it < 16; ++it) {
        int e = packed[it] >> 10;
        int r = packed[it] & 1023;
        int pos = (__shfl(S, e) + r) & (TPB - 1);     // defensive mask
        sbuf[pos] = (e << 12) | (wloc + it * 64 + lane);
    }
    __syncthreads();

    // phase D: sequential LDS read, segmented-contiguous global write
    const int bstart = b * TPB;
#pragma unroll
    for (int k = 0; k < 16; ++k) {
        int j = k * THREADS + tid;
        int p = sbuf[j];
        int e = (p >> 12) & 63;                       // defensive clamp
        int d = __shfl(dbase, e);                     // dbase identical across waves
        sorted[d + j] = bstart + (p & 0xfff);
    }

    // epilogue A: this block's slice of expert_ids
    int total = cps[NE];
    if (tid < epb) {
        int j = b * epb + tid;
        if (j < nb) {
            int bs2 = j * BLK, r = 0;
            if (bs2 < total) {
                int lo = 0, hi = E;
                while (lo < hi) { int mid = (lo + hi) >> 1; if (cps[mid] <= bs2) lo = mid + 1; else hi = mid; }
                r = lo;
            }
            eids[j] = r;
        }
    }
    // epilogue B: pad-gap fill (blocks 0..64) and tail fill (blocks 65..97)
    if (b < E) {
        int cc = counts[b];
        int pe = (cc + BLK - 1) & ~(BLK - 1);
        int len = pe - cc;                            // <= 127
        if (tid < len) sorted[off_pad[b] + cc + tid] = T;
    } else if (b < E + 33) {
        int i = total + (b - E) * THREADS + tid;
        if (i < M) sorted[i] = T;                     // tail <= 8255 < 33*256
    }
}

extern "C" void kernel_launch(void* const* d_in, const int* in_sizes, int n_in,
                              void* d_out, int out_size, void* d_ws, size_t ws_size,
                              hipStream_t stream) {
    const int* topk = (const int*)d_in[0];
    const int T = in_sizes[0];                       // 8388608 = 2048 * 4096
    const int M = T + E * (BLK - 1);
    const int nb = M / BLK;

    int* out = (int*)d_out;
    int* sorted = out;
    int* expert_ids = out + M;
    int* npp = out + M + nb;

    const int NB = T / TPB;                          // 2048 blocks
    const int NC = NB / CHB;                         // 32 chunks
    const int epb = (nb + NB - 1) / NB;              // expert_ids entries per block

    int* bcnt    = (int*)d_ws;                       // NB*NE (becomes in-chunk prefix)
    int* ctot    = bcnt + (size_t)NB * NE;           // NC*NE
    int* counts  = ctot + (size_t)NC * NE;           // E
    int* off_pad = counts + E;                       // E
    int* cum_pad = off_pad + E;                      // E

    k_hist<<<NB, THREADS, 0, stream>>>(topk, bcnt);
    k_scan1<<<NC, THREADS, 0, stream>>>(bcnt, ctot);
    k_scan2<<<1, THREADS, 0, stream>>>(ctot, counts, off_pad, cum_pad, npp, NC);
    k_sort<<<NB, THREADS, 0, stream>>>(topk, bcnt, ctot, counts, off_pad, cum_pad,
                                       sorted, expert_ids, nb, M, T, epb);
}

// Round 9
// 38.546 us; speedup vs baseline: 2.0685x; 1.1651x over previous
//
#include <hip/hip_runtime.h>
#include <stdint.h>

#define NE 64        // real experts (ids in [0,64))
#define E  65        // num_experts + 1 (expert 64 always empty)
#define BLK 128      // block_size
#define WPB 4        // waves per 256-thread block
#define THREADS 256
#define TPB 4096     // tokens per block
#define CHB 64       // blocks per scan chunk

// ---- k_hist: per-block histogram via per-wave LDS atomics -> bcnt[b][e] ----
__global__ void __launch_bounds__(THREADS, 8) k_hist(const int* __restrict__ topk,
                                                     int* __restrict__ bcnt) {
    __shared__ int hist[WPB][NE];
    const int tid = threadIdx.x, w = tid >> 6, lane = tid & 63;
    hist[w][lane] = 0;                       // wave-private row, no barrier needed
    const int base = blockIdx.x * TPB + w * 1024;
#pragma unroll
    for (int it = 0; it < 4; ++it) {
        int4 v = *(const int4*)(topk + base + it * 256 + lane * 4);
        atomicAdd(&hist[w][v.x & 63], 1);
        atomicAdd(&hist[w][v.y & 63], 1);
        atomicAdd(&hist[w][v.z & 63], 1);
        atomicAdd(&hist[w][v.w & 63], 1);
    }
    __syncthreads();
    if (tid < NE)
        bcnt[blockIdx.x * NE + tid] =
            hist[0][tid] + hist[1][tid] + hist[2][tid] + hist[3][tid];
}

// ---- k_scan1: in-chunk exclusive prefix of bcnt over CHB blocks; chunk totals ----
__global__ void k_scan1(int* __restrict__ bcnt, int* __restrict__ ctot) {
    __shared__ int tile[CHB * NE];           // 16 KB
    const int c = blockIdx.x, tid = threadIdx.x;
    for (int i = tid; i < CHB * NE; i += THREADS) tile[i] = bcnt[c * CHB * NE + i];
    __syncthreads();
    if (tid < NE) {
        int acc = 0;
#pragma unroll 8
        for (int j = 0; j < CHB; ++j) { int o = tile[j * NE + tid]; tile[j * NE + tid] = acc; acc += o; }
        ctot[c * NE + tid] = acc;
    }
    __syncthreads();
    for (int i = tid; i < CHB * NE; i += THREADS) bcnt[c * CHB * NE + i] = tile[i];
}

// ---- k_scan2: chunk-level scan + counts / off_pad / cum_pad / npp ----
__global__ void k_scan2(int* __restrict__ ctot, int* __restrict__ counts,
                        int* __restrict__ off_pad, int* __restrict__ cum_pad,
                        int* __restrict__ npp, int nc) {
    __shared__ int ct[32 * NE];              // nc <= 32
    const int tid = threadIdx.x;
    for (int i = tid; i < nc * NE; i += THREADS) ct[i] = ctot[i];
    __syncthreads();
    if (tid < NE) {
        int acc = 0;
        for (int c = 0; c < nc; ++c) { int o = ct[c * NE + tid]; ct[c * NE + tid] = acc; acc += o; }
        counts[tid] = acc;
    }
    if (tid == NE) counts[NE] = 0;           // expert 64 never occurs
    __syncthreads();
    for (int i = tid; i < nc * NE; i += THREADS) ctot[i] = ct[i];
    if (tid == 0) {
        int run = 0;
        for (int e = 0; e < E; ++e) {
            int p = (counts[e] + BLK - 1) & ~(BLK - 1);
            off_pad[e] = run;
            run += p;
            cum_pad[e] = run;
        }
        *npp = run;
    }
}

// ---- k_sort: fused rank (per-lane ds_add_rtn) + block-staged scatter ----
// Rank core: r = atomicAdd(&lrun[w][e], 1). Same-wave DS instructions are
// program-ordered; colliding lanes within one instruction are serialized in
// ascending lane order (HW property under test) -> token order == rank order.
__global__ void __launch_bounds__(THREADS) k_sort(
        const int* __restrict__ topk, const int* __restrict__ bpre,
        const int* __restrict__ ctot, const int* __restrict__ counts,
        const int* __restrict__ off_pad, const int* __restrict__ cum_pad,
        int* __restrict__ sorted, int* __restrict__ eids,
        int nb, int M, int T, int epb) {
    __shared__ int lrun[WPB][NE];    // per-wave running counters (rank core)
    __shared__ int wt[WPB][NE];      // wave totals
    __shared__ int sbuf[TPB];        // 16 KB staged sorted tokens
    __shared__ int cps[E];
    const int tid = threadIdx.x, w = tid >> 6, lane = tid & 63;
    const int b = blockIdx.x, c = b / CHB;

    if (tid < E) cps[tid] = cum_pad[tid];
    lrun[w][lane] = 0;               // wave-private row: same-wave DS order, no barrier

    const int wstart = b * TPB + w * 1024;

    // phase A: stable local ranks via raw per-lane LDS atomic-return
    int packed[16];
#pragma unroll
    for (int it = 0; it < 16; ++it) {
        int e = topk[wstart + it * 64 + lane] & 63;
        int r = atomicAdd(&lrun[w][e], 1);           // rank base, lane-ordered
        packed[it] = (e << 10) | r;                  // wave-local rank < 1024
    }
    wt[w][lane] = lrun[w][lane];
    __syncthreads();

    // phase B: cross-wave offsets + block-local segment starts (lane owns expert lane)
    int woff = 0, btot = 0;
#pragma unroll
    for (int w2 = 0; w2 < WPB; ++w2) { int v = wt[w2][lane]; woff += (w2 < w) ? v : 0; btot += v; }
    int incl = btot;
#pragma unroll
    for (int d = 1; d < 64; d <<= 1) { int t = __shfl_up(incl, d); if (lane >= d) incl += t; }
    int loc = incl - btot;                            // block-local segment start
    int dbase = off_pad[lane] + ctot[c * NE + lane] + bpre[b * NE + lane] - loc;
    int S = loc + woff;                               // this wave's start in segment

    // phase C: place block-local token ids into LDS in sorted order
    const int wloc = w * 1024;
#pragma unroll
    for (int it = 0; it < 16; ++it) {
        int e = packed[it] >> 10;
        int r = packed[it] & 1023;
        int pos = (__shfl(S, e) + r) & (TPB - 1);     // defensive mask
        sbuf[pos] = (e << 12) | (wloc + it * 64 + lane);
    }
    __syncthreads();

    // phase D: sequential LDS read, segmented-contiguous global write
    const int bstart = b * TPB;
#pragma unroll
    for (int k = 0; k < 16; ++k) {
        int j = k * THREADS + tid;
        int p = sbuf[j];
        int e = (p >> 12) & 63;                       // defensive clamp
        int d = __shfl(dbase, e);                     // dbase identical across waves
        sorted[d + j] = bstart + (p & 0xfff);
    }

    // epilogue A: this block's slice of expert_ids
    int total = cps[NE];
    if (tid < epb) {
        int j = b * epb + tid;
        if (j < nb) {
            int bs2 = j * BLK, r = 0;
            if (bs2 < total) {
                int lo = 0, hi = E;
                while (lo < hi) { int mid = (lo + hi) >> 1; if (cps[mid] <= bs2) lo = mid + 1; else hi = mid; }
                r = lo;
            }
            eids[j] = r;
        }
    }
    // epilogue B: pad-gap fill (blocks 0..64) and tail fill (blocks 65..97)
    if (b < E) {
        int cc = counts[b];
        int pe = (cc + BLK - 1) & ~(BLK - 1);
        int len = pe - cc;                            // <= 127
        if (tid < len) sorted[off_pad[b] + cc + tid] = T;
    } else if (b < E + 33) {
        int i = total + (b - E) * THREADS + tid;
        if (i < M) sorted[i] = T;                     // tail <= 8255 < 33*256
    }
}

extern "C" void kernel_launch(void* const* d_in, const int* in_sizes, int n_in,
                              void* d_out, int out_size, void* d_ws, size_t ws_size,
                              hipStream_t stream) {
    const int* topk = (const int*)d_in[0];
    const int T = in_sizes[0];                       // 8388608 = 2048 * 4096
    const int M = T + E * (BLK - 1);
    const int nb = M / BLK;

    int* out = (int*)d_out;
    int* sorted = out;
    int* expert_ids = out + M;
    int* npp = out + M + nb;

    const int NB = T / TPB;                          // 2048 blocks
    const int NC = NB / CHB;                         // 32 chunks
    const int epb = (nb + NB - 1) / NB;              // expert_ids entries per block

    int* bcnt    = (int*)d_ws;                       // NB*NE (becomes in-chunk prefix)
    int* ctot    = bcnt + (size_t)NB * NE;           // NC*NE
    int* counts  = ctot + (size_t)NC * NE;           // E
    int* off_pad = counts + E;                       // E
    int* cum_pad = off_pad + E;                      // E

    k_hist<<<NB, THREADS, 0, stream>>>(topk, bcnt);
    k_scan1<<<NC, THREADS, 0, stream>>>(bcnt, ctot);
    k_scan2<<<1, THREADS, 0, stream>>>(ctot, counts, off_pad, cum_pad, npp, NC);
    k_sort<<<NB, THREADS, 0, stream>>>(topk, bcnt, ctot, counts, off_pad, cum_pad,
                                       sorted, expert_ids, nb, M, T, epb);
}

// Round 10
// 38.463 us; speedup vs baseline: 2.0730x; 1.0022x over previous
//
#include <hip/hip_runtime.h>
#include <hip/hip_cooperative_groups.h>
#include <stdint.h>

namespace cg = cooperative_groups;

#define NE 64        // real experts (ids in [0,64))
#define E  65        // num_experts + 1 (expert 64 always empty)
#define BLK 128      // block_size
#define WPB 4        // waves per 256-thread block
#define THREADS 256

// fused-path geometry
#define FTPB 8192    // tokens per block
#define FNB  1024    // blocks (must all be co-resident)
#define FITS 32      // tokens per lane
#define FCHB 64      // blocks per scan chunk
#define FNC  16      // chunks

// fallback-path geometry (R9, proven)
#define TPB 4096
#define CHB 64

// =============================== fused path ===============================
__global__ void __launch_bounds__(THREADS) k_fused(
        const int* __restrict__ topk, int* __restrict__ bcnt, int* __restrict__ ctot,
        int* __restrict__ sorted, int* __restrict__ eids, int* __restrict__ npp,
        int nb, int M, int T, int epb) {
    __shared__ int lrun[WPB][NE];   // per-wave running counters
    __shared__ int wt[WPB][NE];     // wave totals
    __shared__ int sbuf[FTPB];      // 32 KB: scan tile (phase 2) / staging (phase 3)
    __shared__ int cps[E];          // cum_pad for epilogues
    const int tid = threadIdx.x, w = tid >> 6, lane = tid & 63;
    const int b = blockIdx.x, c = b >> 6;      // chunk = b / FCHB
    cg::grid_group grid = cg::this_grid();

    lrun[w][lane] = 0;              // wave-private row: same-wave DS order, no barrier
    const int wstart = b * FTPB + w * 2048;

    // ---- phase 1: stable wave-local ranks via ds_add_rtn (lane-ordered) ----
    int packed[FITS];
#pragma unroll
    for (int it = 0; it < FITS; ++it) {
        int e = topk[wstart + it * 64 + lane] & 63;
        int r = atomicAdd(&lrun[w][e], 1);      // rank, ascending (it, lane) order
        packed[it] = (e << 11) | r;             // r < 2048
    }
    wt[w][lane] = lrun[w][lane];
    __syncthreads();

    int woff = 0, btot = 0;                     // lane owns expert `lane`
#pragma unroll
    for (int w2 = 0; w2 < WPB; ++w2) { int v = wt[w2][lane]; woff += (w2 < w) ? v : 0; btot += v; }
    if (w == 0) bcnt[b * NE + lane] = btot;     // publish block totals
    int incl = btot;                            // block-local segment starts
#pragma unroll
    for (int d = 1; d < 64; d <<= 1) { int t = __shfl_up(incl, d); if (lane >= d) incl += t; }
    int loc = incl - btot;
    int S = loc + woff;                         // this wave's start in block segment

    grid.sync();

    // ---- phase 2: blocks 0..15 scan 64 consecutive bcnt rows (coalesced) ----
    if (b < FNC) {
        for (int i = tid; i < FCHB * NE; i += THREADS) sbuf[i] = bcnt[b * FCHB * NE + i];
        __syncthreads();
        if (tid < NE) {
            int acc = 0;
#pragma unroll 8
            for (int j = 0; j < FCHB; ++j) { int o = sbuf[j * NE + tid]; sbuf[j * NE + tid] = acc; acc += o; }
            ctot[b * NE + tid] = acc;
        }
        __syncthreads();
        for (int i = tid; i < FCHB * NE; i += THREADS) bcnt[b * FCHB * NE + i] = sbuf[i];
    }

    grid.sync();

    // ---- phase 3 prologue: replicated global metadata (no third sync) ----
    int ct_pre = 0, cnt_tot = 0;                // lane owns expert `lane`
#pragma unroll
    for (int k = 0; k < FNC; ++k) {
        int v = ctot[k * NE + lane];
        ct_pre += (k < c) ? v : 0;
        cnt_tot += v;
    }
    int padded = (cnt_tot + BLK - 1) & ~(BLK - 1);
    int incl2 = padded;
#pragma unroll
    for (int d = 1; d < 64; d <<= 1) { int t = __shfl_up(incl2, d); if (lane >= d) incl2 += t; }
    int off_lane = incl2 - padded;              // off_pad[lane]
    int total = __shfl(incl2, 63);              // num_tokens_post_pad
    if (w == 0) cps[lane] = incl2;              // cum_pad[0..63]
    if (tid == 0) cps[NE] = total;              // cum_pad[64] == total

    int dbase = off_lane + ct_pre + bcnt[b * NE + lane] - loc;

    // ---- phase C: place block-local token ids into LDS in sorted order ----
    const int wloc = w * 2048;
#pragma unroll
    for (int it = 0; it < FITS; ++it) {
        int e = packed[it] >> 11;
        int r = packed[it] & 2047;
        int pos = (__shfl(S, e) + r) & (FTPB - 1);   // defensive mask
        sbuf[pos] = (e << 13) | (wloc + it * 64 + lane);
    }
    __syncthreads();

    // ---- phase D: sequential LDS read, segmented-contiguous global write ----
    const int bstart = b * FTPB;
#pragma unroll
    for (int k = 0; k < FITS; ++k) {
        int j = k * THREADS + tid;
        int p = sbuf[j];
        int e = (p >> 13) & 63;                      // defensive clamp
        int d = __shfl(dbase, e);                    // identical across waves
        sorted[d + j] = bstart + (p & (FTPB - 1));
    }

    // ---- epilogue A: this block's slice of expert_ids ----
    if (tid < epb) {
        int j = b * epb + tid;
        if (j < nb) {
            int bs2 = j * BLK, r = 0;
            if (bs2 < total) {
                int lo = 0, hi = E;
                while (lo < hi) { int mid = (lo + hi) >> 1; if (cps[mid] <= bs2) lo = mid + 1; else hi = mid; }
                r = lo;
            }
            eids[j] = r;
        }
    }
    // ---- epilogue B: pad-gap fill (blocks 0..63) and tail fill ----
    if (b < NE) {
        int cc = __shfl(cnt_tot, b);            // counts[b]
        int ob = __shfl(off_lane, b);           // off_pad[b]
        int pe = (cc + BLK - 1) & ~(BLK - 1);
        int len = pe - cc;                      // <= 127
        if (tid < len) sorted[ob + cc + tid] = T;
    } else if (b >= E && b < E + 33) {
        int i = total + (b - E) * THREADS + tid;
        if (i < M) sorted[i] = T;               // tail <= 8255 < 33*256
    }
    if (b == 0 && tid == 0) *npp = total;
}

// ============================ fallback path (R9) ============================
__global__ void __launch_bounds__(THREADS, 8) k_hist(const int* __restrict__ topk,
                                                     int* __restrict__ bcnt) {
    __shared__ int hist[WPB][NE];
    const int tid = threadIdx.x, w = tid >> 6, lane = tid & 63;
    hist[w][lane] = 0;
    const int base = blockIdx.x * TPB + w * 1024;
#pragma unroll
    for (int it = 0; it < 4; ++it) {
        int4 v = *(const int4*)(topk + base + it * 256 + lane * 4);
        atomicAdd(&hist[w][v.x & 63], 1);
        atomicAdd(&hist[w][v.y & 63], 1);
        atomicAdd(&hist[w][v.z & 63], 1);
        atomicAdd(&hist[w][v.w & 63], 1);
    }
    __syncthreads();
    if (tid < NE)
        bcnt[blockIdx.x * NE + tid] =
            hist[0][tid] + hist[1][tid] + hist[2][tid] + hist[3][tid];
}

__global__ void k_scan1(int* __restrict__ bcnt, int* __restrict__ ctot) {
    __shared__ int tile[CHB * NE];
    const int c = blockIdx.x, tid = threadIdx.x;
    for (int i = tid; i < CHB * NE; i += THREADS) tile[i] = bcnt[c * CHB * NE + i];
    __syncthreads();
    if (tid < NE) {
        int acc = 0;
#pragma unroll 8
        for (int j = 0; j < CHB; ++j) { int o = tile[j * NE + tid]; tile[j * NE + tid] = acc; acc += o; }
        ctot[c * NE + tid] = acc;
    }
    __syncthreads();
    for (int i = tid; i < CHB * NE; i += THREADS) bcnt[c * CHB * NE + i] = tile[i];
}

__global__ void k_scan2(int* __restrict__ ctot, int* __restrict__ counts,
                        int* __restrict__ off_pad, int* __restrict__ cum_pad,
                        int* __restrict__ npp, int nc) {
    __shared__ int ct[32 * NE];
    const int tid = threadIdx.x;
    for (int i = tid; i < nc * NE; i += THREADS) ct[i] = ctot[i];
    __syncthreads();
    if (tid < NE) {
        int acc = 0;
        for (int c = 0; c < nc; ++c) { int o = ct[c * NE + tid]; ct[c * NE + tid] = acc; acc += o; }
        counts[tid] = acc;
    }
    if (tid == NE) counts[NE] = 0;
    __syncthreads();
    for (int i = tid; i < nc * NE; i += THREADS) ctot[i] = ct[i];
    if (tid == 0) {
        int run = 0;
        for (int e = 0; e < E; ++e) {
            int p = (counts[e] + BLK - 1) & ~(BLK - 1);
            off_pad[e] = run; run += p; cum_pad[e] = run;
        }
        *npp = run;
    }
}

__global__ void __launch_bounds__(THREADS) k_sort(
        const int* __restrict__ topk, const int* __restrict__ bpre,
        const int* __restrict__ ctot, const int* __restrict__ counts,
        const int* __restrict__ off_pad, const int* __restrict__ cum_pad,
        int* __restrict__ sorted, int* __restrict__ eids,
        int nb, int M, int T, int epb) {
    __shared__ int lrun[WPB][NE];
    __shared__ int wt[WPB][NE];
    __shared__ int sbuf[TPB];
    __shared__ int cps[E];
    const int tid = threadIdx.x, w = tid >> 6, lane = tid & 63;
    const int b = blockIdx.x, c = b / CHB;
    if (tid < E) cps[tid] = cum_pad[tid];
    lrun[w][lane] = 0;
    const int wstart = b * TPB + w * 1024;
    int packed[16];
#pragma unroll
    for (int it = 0; it < 16; ++it) {
        int e = topk[wstart + it * 64 + lane] & 63;
        int r = atomicAdd(&lrun[w][e], 1);
        packed[it] = (e << 10) | r;
    }
    wt[w][lane] = lrun[w][lane];
    __syncthreads();
    int woff = 0, btot = 0;
#pragma unroll
    for (int w2 = 0; w2 < WPB; ++w2) { int v = wt[w2][lane]; woff += (w2 < w) ? v : 0; btot += v; }
    int incl = btot;
#pragma unroll
    for (int d = 1; d < 64; d <<= 1) { int t = __shfl_up(incl, d); if (lane >= d) incl += t; }
    int loc = incl - btot;
    int dbase = off_pad[lane] + ctot[c * NE + lane] + bpre[b * NE + lane] - loc;
    int S = loc + woff;
    const int wloc = w * 1024;
#pragma unroll
    for (int it = 0; it < 16; ++it) {
        int e = packed[it] >> 10;
        int r = packed[it] & 1023;
        int pos = (__shfl(S, e) + r) & (TPB - 1);
        sbuf[pos] = (e << 12) | (wloc + it * 64 + lane);
    }
    __syncthreads();
    const int bstart = b * TPB;
#pragma unroll
    for (int k = 0; k < 16; ++k) {
        int j = k * THREADS + tid;
        int p = sbuf[j];
        int e = (p >> 12) & 63;
        int d = __shfl(dbase, e);
        sorted[d + j] = bstart + (p & 0xfff);
    }
    int total = cps[NE - 1];
    if (tid < epb) {
        int j = b * epb + tid;
        if (j < nb) {
            int bs2 = j * BLK, r = 0;
            if (bs2 < total) {
                int lo = 0, hi = E;
                while (lo < hi) { int mid = (lo + hi) >> 1; if (cps[mid] <= bs2) lo = mid + 1; else hi = mid; }
                r = lo;
            }
            eids[j] = r;
        }
    }
    if (b < E) {
        int cc = counts[b];
        int pe = (cc + BLK - 1) & ~(BLK - 1);
        int len = pe - cc;
        if (tid < len) sorted[off_pad[b] + cc + tid] = T;
    } else if (b < E + 33) {
        int i = total + (b - E) * THREADS + tid;
        if (i < M) sorted[i] = T;
    }
}

extern "C" void kernel_launch(void* const* d_in, const int* in_sizes, int n_in,
                              void* d_out, int out_size, void* d_ws, size_t ws_size,
                              hipStream_t stream) {
    const int* topk = (const int*)d_in[0];
    const int T = in_sizes[0];                       // 8388608
    const int M = T + E * (BLK - 1);
    const int nb = M / BLK;

    int* out = (int*)d_out;
    int* sorted = out;
    int* expert_ids = out + M;
    int* npp = out + M + nb;

    int* bcnt = (int*)d_ws;

    // ---- try fused cooperative path ----
    bool fused_ok = (T == FNB * FTPB);
    if (fused_ok) {
        size_t need = ((size_t)FNB * NE + (size_t)FNC * NE) * sizeof(int);
        if (need > ws_size) fused_ok = false;
    }
    if (fused_ok) {
        int maxb = 0;
        if (hipOccupancyMaxActiveBlocksPerMultiprocessor(&maxb, k_fused, THREADS, 0) != hipSuccess)
            fused_ok = false;
        int dev = 0, cus = 0;
        hipGetDevice(&dev);
        if (fused_ok && hipDeviceGetAttribute(&cus, hipDeviceAttributeMultiprocessorCount, dev) != hipSuccess)
            fused_ok = false;
        if (fused_ok && (long long)maxb * cus < FNB) fused_ok = false;
    }

    if (fused_ok) {
        int* ctot = bcnt + (size_t)FNB * NE;
        const int epb = (nb + FNB - 1) / FNB;        // 65
        const int* topk_a = topk; int* bcnt_a = bcnt; int* ctot_a = ctot;
        int* sorted_a = sorted; int* eids_a = expert_ids; int* npp_a = npp;
        int nb_a = nb, M_a = M, T_a = T, epb_a = epb;
        void* args[] = {(void*)&topk_a, (void*)&bcnt_a, (void*)&ctot_a,
                        (void*)&sorted_a, (void*)&eids_a, (void*)&npp_a,
                        (void*)&nb_a, (void*)&M_a, (void*)&T_a, (void*)&epb_a};
        if (hipLaunchCooperativeKernel((void*)k_fused, dim3(FNB), dim3(THREADS),
                                       args, 0, stream) == hipSuccess)
            return;
    }

    // ---- fallback: proven R9 4-kernel path ----
    const int NB = T / TPB;
    const int NC = NB / CHB;
    const int epb = (nb + NB - 1) / NB;
    int* ctot    = bcnt + (size_t)NB * NE;
    int* counts  = ctot + (size_t)NC * NE;
    int* off_pad = counts + E;
    int* cum_pad = off_pad + E;

    k_hist<<<NB, THREADS, 0, stream>>>(topk, bcnt);
    k_scan1<<<NC, THREADS, 0, stream>>>(bcnt, ctot);
    k_scan2<<<1, THREADS, 0, stream>>>(ctot, counts, off_pad, cum_pad, npp, NC);
    k_sort<<<NB, THREADS, 0, stream>>>(topk, bcnt, ctot, counts, off_pad, cum_pad,
                                       sorted, expert_ids, nb, M, T, epb);
}